// Round 5
// baseline (1665.956 us; speedup 1.0000x reference)
//
#include <hip/hip_runtime.h>
#include <hip/hip_bf16.h>
#include <cstdint>
#include <cstddef>

typedef float  f32x4  __attribute__((ext_vector_type(4)));
typedef __bf16 bf16x8 __attribute__((ext_vector_type(8)));

#define DEV __device__ __forceinline__

DEV float gelu_f(float x){ return 0.5f * x * (1.0f + erff(x * 0.70710678118654752f)); }

// s_waitcnt imm (gfx9 enc): vmcnt[3:0]|[15:14], expcnt[6:4], lgkmcnt[11:8]
#define WAIT_VM12 0x0F7C  // vmcnt(12), lgkm/exp no-wait
#define WAIT_VM0  0x0F70  // vmcnt(0),  lgkm/exp no-wait

// async global->LDS, 16B/lane; LDS dest = wave-uniform base + lane*16
DEV void gl16(void* lds, const void* g){
  __builtin_amdgcn_global_load_lds((const __attribute__((address_space(1))) void*)g,
                                   (__attribute__((address_space(3))) void*)lds, 16, 0, 0);
}

// ---------------- workspace layout (bytes) ----------------
static constexpr size_t OFF_FX     = 0;                       // fx fp32 [16384,512]     33554432
static constexpr size_t OFF_H      = 33554432;                // h bf16 [16384,512]      16777216
static constexpr size_t OFF_REGA   = 50331648;                // 67108864 region
static constexpr size_t OFF_COMB   = OFF_REGA;                // fp32 [16384,768] (fx_mid 0-511 | logits 512-767)
static constexpr size_t OFF_SW     = OFF_REGA + 50331648;     // fp32 [16,8192,32]       16777216
static constexpr size_t OFF_MLPH   = OFF_REGA;                // bf16 [16384,2048] (after comb/sw dead)
static constexpr size_t OFF_H1     = OFF_REGA;                // bf16 [16384,1024] (preprocess only)
static constexpr size_t OFF_OUTB   = OFF_REGA + 67108864;     // bf16 [16384,512]        16777216
static constexpr size_t OFF_PT     = OFF_OUTB + 16777216;     // fp32 [16,16,32,64]      2097152
static constexpr size_t OFF_PTM    = OFF_PT + 2097152;        // fp32 [16,16,32]         32768
static constexpr size_t OFF_OT     = OFF_PTM + 32768;         // fp32 [16,32,64]         131072
static constexpr size_t OFF_WT     = OFF_OT + 131072;         // bf16 weights (22 MB)
static constexpr size_t OFF_BIAS   = OFF_WT + 23068672;       // bcat[4][768] f32, then bpre2p[512] f32

// ---------------- weight prep ----------------
__global__ __launch_bounds__(256) void wtrans_k(const float* __restrict__ W, __bf16* __restrict__ Wt,
                                                int K, int N, size_t wstride, size_t wtstride)
{
  __shared__ float tile[64][65];
  W  += (size_t)blockIdx.z * wstride;
  Wt += (size_t)blockIdx.z * wtstride;
  int t = threadIdx.x;
  int k0 = blockIdx.x * 64, n0 = blockIdx.y * 64;
  #pragma unroll
  for (int i = 0; i < 16; i++){
    int e = t + 256*i; int kk = e >> 6, nn = e & 63;
    tile[kk][nn] = W[(size_t)(k0+kk)*N + n0+nn];
  }
  __syncthreads();
  #pragma unroll
  for (int i = 0; i < 16; i++){
    int e = t + 256*i; int nn = e >> 6, kk = e & 63;
    Wt[(size_t)(n0+nn)*K + k0+kk] = (__bf16)tile[kk][nn];
  }
}

// Wxst -> rows 512+hg of Btcat[l]; blog -> bcat[l][512+hg]
__global__ __launch_bounds__(128) void prep_wxs_k(const float* __restrict__ Wx, const float* __restrict__ Wsl,
                                                  const float* __restrict__ bx, const float* __restrict__ bsl,
                                                  const float* __restrict__ temp,
                                                  __bf16* __restrict__ Btcat, float* __restrict__ bcat)
{
  __shared__ float wsc[64];
  int l = blockIdx.y;
  const float* Wx_l  = Wx  + (size_t)l*262144;
  const float* Wsl_l = Wsl + l*2048;
  const float* bx_l  = bx  + l*512;
  const float* bsl_l = bsl + l*32;
  __bf16* Wt_l = Btcat + (size_t)l*393216 + (size_t)512*512;
  float* blog_l = bcat + l*768 + 512;
  int hg = blockIdx.x; int h = hg >> 5, g = hg & 31;
  int t = threadIdx.x;
  if (t < 64) wsc[t] = Wsl_l[t*32 + g];
  __syncthreads();
  float invt = 1.0f / temp[l*8 + h];
  #pragma unroll
  for (int cc = 0; cc < 4; cc++){
    int c = t + cc*128;
    float a = 0.f;
    for (int d = 0; d < 64; d++) a += Wx_l[(size_t)c*512 + h*64 + d] * wsc[d];
    Wt_l[(size_t)hg*512 + c] = (__bf16)(a * invt);
  }
  if (t == 0){
    float a = 0.f;
    for (int d = 0; d < 64; d++) a += bx_l[h*64 + d] * wsc[d];
    blog_l[hg] = (a + bsl_l[g]) * invt;
  }
}

__global__ __launch_bounds__(256) void bias_setup_k(const float* __restrict__ b_pre2, const float* __restrict__ placeholder,
                                                    const float* __restrict__ bfx,
                                                    float* __restrict__ bpre2p, float* __restrict__ bcat)
{
  int i = blockIdx.x*256 + threadIdx.x;   // 0..2559
  if (i < 512) bpre2p[i] = b_pre2[i] + placeholder[i];
  else if (i < 2560){
    int j = i - 512; int l = j >> 9, c = j & 511;
    bcat[l*768 + c] = bfx[l*512 + c];
  }
}

// ---------------- preprocess stage 1 ----------------
__global__ __launch_bounds__(256) void preproc1_k(const float* __restrict__ fun, const float* __restrict__ emb,
                                                  const float* __restrict__ W1, const float* __restrict__ b1,
                                                  __bf16* __restrict__ h1)
{
  __shared__ float w1l[10][1024];
  int t = threadIdx.x;
  for (int i = t*4; i < 10240; i += 1024) *(f32x4*)&w1l[0][i] = *(const f32x4*)&W1[i];
  __syncthreads();
  f32x4 bv = *(const f32x4*)&b1[t*4];
  int r0 = blockIdx.x * 4;
  for (int r = 0; r < 4; r++){
    int m = r0 + r;
    const float* er = emb + (size_t)m*3;
    const float* fr = fun + (size_t)m*7;
    float x[10];
    x[0]=er[0]; x[1]=er[1]; x[2]=er[2];
    #pragma unroll
    for (int c = 0; c < 7; c++) x[3+c] = fr[c];
    f32x4 acc = bv;
    #pragma unroll
    for (int c = 0; c < 10; c++){
      f32x4 wv = *(const f32x4*)&w1l[c][t*4];
      acc += x[c] * wv;
    }
    __bf16* op = h1 + (size_t)m*1024 + t*4;
    #pragma unroll
    for (int e = 0; e < 4; e++) op[e] = (__bf16)gelu_f(acc[e]);
  }
}

// ---------------- persistent MFMA GEMM, depth-4 gl_lds pipeline ----------------
// D[M=16384,N] = A[M,K]@Bt[N,K]^T + epilogue. Grid = 512 blocks (2/CU), each loops
// tiles tile = bid + j*512 (tm = bid&127 constant -> A-slab L2-hot across its tiles).
// Flat stage stream (tile-major, k-minor) prefetched 3 iters ahead; constant
// vmcnt(12) waits; tail stages clamp addresses (land in dead buffers only).
// K, niter are powers of 2: lgK = log2(K), lgni = log2(K/32).
template<int EPI>
__global__ __launch_bounds__(256) void gemm_persist(const __bf16* __restrict__ A, const __bf16* __restrict__ Bt,
                                                    const float* __restrict__ bias, const float* __restrict__ res,
                                                    void* __restrict__ outp, int N, int lgK, int lgni, int ntot)
{
  __shared__ bf16x8 ldsA[4][8][64];   // [buf][subtile][lane]
  __shared__ bf16x8 ldsB[4][8][64];
  const int tid = threadIdx.x;
  const int w = tid >> 6, lane = tid & 63;
  const int lm = lane & 15, lq = lane >> 4;
  const int wm = (w >> 1) * 64, wn = (w & 1) * 64;
  const int s0 = w*2, s1 = s0 + 1;
  const int bid = blockIdx.x;
  const int niter = 1 << lgni;
  const int nstage = (((ntot - bid + 511) >> 9) << lgni);   // this block's stages
  const int smax = nstage - 1;

  // per-wave invariant parts of the staging addresses
  const int arow_off = s0*16 + lm;        // within-tile A row staged by this wave
  const int lqo = lq*8;

  auto issue = [&](int s){
    int sc = s <= smax ? s : smax;
    int j  = sc >> lgni;
    int kk = (sc & (niter-1)) << 5;
    int tile = bid + (j << 9);
    int tm = tile & 127, tn = tile >> 7;
    const __bf16* Ap = A  + (((size_t)((tm << 7) + arow_off) << lgK) + kk + lqo);
    const __bf16* Bp = Bt + (((size_t)((tn << 7) + arow_off) << lgK) + kk + lqo);
    int buf = s & 3;
    gl16(&ldsA[buf][s0][0], Ap);
    gl16(&ldsA[buf][s1][0], Ap + ((size_t)16 << lgK));
    gl16(&ldsB[buf][s0][0], Bp);
    gl16(&ldsB[buf][s1][0], Bp + ((size_t)16 << lgK));
  };

  issue(0); issue(1); issue(2);

  f32x4 acc[4][4] = {};

  for (int i = 0; i < nstage; ++i){
    issue(i + 3);
    __builtin_amdgcn_s_waitcnt(WAIT_VM12);   // stage i's 16 loads (4 per wave) done
    __builtin_amdgcn_s_barrier();            // visible to all waves
    const int buf = i & 3;
    bf16x8 af[4], bfr[4];
    #pragma unroll
    for (int ii = 0; ii < 4; ii++) af[ii]  = ldsA[buf][(wm>>4) + ii][lane];
    #pragma unroll
    for (int jj = 0; jj < 4; jj++) bfr[jj] = ldsB[buf][(wn>>4) + jj][lane];
    #pragma unroll
    for (int ii = 0; ii < 4; ii++)
      #pragma unroll
      for (int jj = 0; jj < 4; jj++)
        acc[ii][jj] = __builtin_amdgcn_mfma_f32_16x16x32_bf16(af[ii], bfr[jj], acc[ii][jj], 0, 0, 0);

    if ((i & (niter-1)) == niter-1){
      // epilogue for completed tile; overlaps with in-flight prefetch of next tile
      int tile = bid + ((i >> lgni) << 9);
      int m0 = (tile & 127) << 7, n0 = (tile >> 7) << 7;
      #pragma unroll
      for (int ii = 0; ii < 4; ii++){
        int row0 = m0 + wm + ii*16 + lq*4;
        #pragma unroll
        for (int jj = 0; jj < 4; jj++){
          int col = n0 + wn + jj*16 + lm;
          float bv = bias[col];
          #pragma unroll
          for (int r = 0; r < 4; r++){
            size_t idx = (size_t)(row0 + r)*N + col;
            float v = acc[ii][jj][r] + bv;
            if (EPI == 2) v += res[idx];
            if (EPI == 1) ((__bf16*)outp)[idx] = (__bf16)gelu_f(v);
            else          ((float*)outp)[idx]  = v;
            acc[ii][jj][r] = 0.f;
          }
        }
      }
    }
    __builtin_amdgcn_s_barrier();            // buf consumed before next iter's DMA may land in it
  }
  __builtin_amdgcn_s_waitcnt(WAIT_VM0);      // drain trailing clamped prefetches
}

// ---------------- LayerNorm (512 cols), fp32 in -> bf16 out; 1 wave/row ----------------
__global__ __launch_bounds__(256) void ln_k(const float* __restrict__ x, const float* __restrict__ g,
                                            const float* __restrict__ b, __bf16* __restrict__ out)
{
  int w = threadIdx.x >> 6, lane = threadIdx.x & 63;
  int row = blockIdx.x*4 + w;
  const float* xr = x + (size_t)row*512 + lane*8;
  float v[8];
  *(f32x4*)&v[0] = *(const f32x4*)xr;
  *(f32x4*)&v[4] = *(const f32x4*)(xr + 4);
  float s = 0.f, sq = 0.f;
  #pragma unroll
  for (int e = 0; e < 8; e++){ s += v[e]; sq += v[e]*v[e]; }
  #pragma unroll
  for (int off = 32; off; off >>= 1){ s += __shfl_xor(s, off); sq += __shfl_xor(sq, off); }
  float mean = s * (1.f/512.f);
  float var  = sq * (1.f/512.f) - mean*mean;
  float rstd = rsqrtf(var + 1e-5f);
  float gv[8], bv[8];
  *(f32x4*)&gv[0] = *(const f32x4*)(g + lane*8);
  *(f32x4*)&gv[4] = *(const f32x4*)(g + lane*8 + 4);
  *(f32x4*)&bv[0] = *(const f32x4*)(b + lane*8);
  *(f32x4*)&bv[4] = *(const f32x4*)(b + lane*8 + 4);
  __bf16* op = out + (size_t)row*512 + lane*8;
  #pragma unroll
  for (int e = 0; e < 8; e++) op[e] = (__bf16)((v[e]-mean)*rstd*gv[e] + bv[e]);
}

// ---------------- slice softmax: comb[m][512+h*32+g] -> sw[(b*8+h)][n][g] ----------------
__global__ __launch_bounds__(256) void softmax_k(const float* __restrict__ comb, float* __restrict__ sw)
{
  int gid = blockIdx.x*256 + threadIdx.x;   // 16384*8
  int m = gid >> 3, h = gid & 7;
  const float* lp = comb + (size_t)m*768 + 512 + h*32;
  float x[32];
  #pragma unroll
  for (int i = 0; i < 8; i++) *(f32x4*)&x[i*4] = *(const f32x4*)(lp + i*4);
  float mx = x[0];
  #pragma unroll
  for (int i = 1; i < 32; i++) mx = fmaxf(mx, x[i]);
  float s = 0.f;
  #pragma unroll
  for (int i = 0; i < 32; i++){ x[i] = expf(x[i]-mx); s += x[i]; }
  float inv = 1.f / s;
  int b = m >> 13, n = m & 8191;
  float* op = sw + ((size_t)(b*8 + h)*8192 + n)*32;
  #pragma unroll
  for (int i = 0; i < 8; i++){
    f32x4 t = *(f32x4*)&x[i*4];
    t *= inv;
    *(f32x4*)(op + i*4) = t;
  }
}

// ---------------- token partial: per (chunk, bh) accumulate sw^T @ fx_mid over 512 n ----------------
__global__ __launch_bounds__(256) void token_part_k(const float* __restrict__ comb, const float* __restrict__ sw,
                                                    float* __restrict__ pt, float* __restrict__ ptm)
{
  __shared__ float fxl[32][64];
  __shared__ float swl[32][32];
  int t = threadIdx.x;
  int chunk = blockIdx.x, bh = blockIdx.y;
  int b = bh >> 3, h = bh & 7;
  int d = t & 63, gg = (t >> 6) * 8;
  float acc[8] = {0,0,0,0,0,0,0,0};
  float macc = 0.f;
  for (int s = 0; s < 16; s++){
    int nbase = chunk*512 + s*32;
    __syncthreads();
    #pragma unroll
    for (int i = 0; i < 2; i++){
      int e = t + 256*i; int rv = e >> 4, c4 = e & 15;
      *(f32x4*)&fxl[rv][c4*4] = *(const f32x4*)&comb[((size_t)b*8192 + nbase + rv)*768 + h*64 + c4*4];
    }
    { int rv = t >> 3, c4 = t & 7;
      *(f32x4*)&swl[rv][c4*4] = *(const f32x4*)&sw[((size_t)bh*8192 + nbase + rv)*32 + c4*4]; }
    __syncthreads();
    for (int nn = 0; nn < 32; nn++){
      float f = fxl[nn][d];
      #pragma unroll
      for (int jj = 0; jj < 8; jj++) acc[jj] += f * swl[nn][gg+jj];
    }
    if (t < 32){ for (int nn = 0; nn < 32; nn++) macc += swl[nn][t]; }
  }
  int cb = chunk*16 + bh;
  #pragma unroll
  for (int jj = 0; jj < 8; jj++)
    pt[((size_t)cb*32 + gg + jj)*64 + d] = acc[jj];
  if (t < 32) ptm[cb*32 + t] = macc;
}

// ---------------- token reduce + tiny attention per (b,h), fused ----------------
__global__ __launch_bounds__(256) void attn_k(const float* __restrict__ pt, const float* __restrict__ ptm,
                                              const float* __restrict__ Wq, const float* __restrict__ Wk,
                                              const float* __restrict__ Wv, float* __restrict__ ot)
{
  __shared__ float tok[32][64];
  __shared__ float ml[32];
  __shared__ float qq[32][65], kk2[32][65], vv[32][65];
  __shared__ float at[32][33];
  int t = threadIdx.x, bh = blockIdx.x;
  if (t < 32){
    float s = 0.f;
    for (int c = 0; c < 16; c++) s += ptm[(c*16 + bh)*32 + t];
    ml[t] = s + 1e-5f;
  }
  __syncthreads();
  #pragma unroll
  for (int i = 0; i < 8; i++){
    int e = t + 256*i; int g = e >> 6, d = e & 63;
    float s = 0.f;
    for (int c = 0; c < 16; c++) s += pt[((size_t)(c*16 + bh)*32 + g)*64 + d];
    tok[g][d] = s / ml[g];
  }
  __syncthreads();
  #pragma unroll
  for (int i = 0; i < 8; i++){
    int e = t + 256*i; int g = e >> 6, j = e & 63;
    float aq = 0.f, ak = 0.f, av = 0.f;
    for (int d = 0; d < 64; d++){
      float tv = tok[g][d];
      aq += tv * Wq[d*64 + j];
      ak += tv * Wk[d*64 + j];
      av += tv * Wv[d*64 + j];
    }
    qq[g][j] = aq; kk2[g][j] = ak; vv[g][j] = av;
  }
  __syncthreads();
  #pragma unroll
  for (int i = 0; i < 4; i++){
    int e = t + 256*i; int g = e >> 5, j2 = e & 31;
    float s2 = 0.f;
    for (int d = 0; d < 64; d++) s2 += qq[g][d] * kk2[j2][d];
    at[g][j2] = s2 * 0.125f;
  }
  __syncthreads();
  if (t < 32){
    float mx = at[t][0];
    for (int j = 1; j < 32; j++) mx = fmaxf(mx, at[t][j]);
    float ss = 0.f;
    for (int j = 0; j < 32; j++){ float e2 = expf(at[t][j]-mx); at[t][j] = e2; ss += e2; }
    float inv = 1.f / ss;
    for (int j = 0; j < 32; j++) at[t][j] *= inv;
  }
  __syncthreads();
  #pragma unroll
  for (int i = 0; i < 8; i++){
    int e = t + 256*i; int g = e >> 6, d = e & 63;
    float s3 = 0.f;
    for (int j = 0; j < 32; j++) s3 += at[g][j] * vv[j][d];
    ot[(size_t)bh*2048 + e] = s3;
  }
}

// ---------------- de-slice ----------------
__global__ __launch_bounds__(256) void deslice_k(const float* __restrict__ ot, const float* __restrict__ sw,
                                                 __bf16* __restrict__ outb)
{
  __shared__ float otl[32][64];
  __shared__ float swl[4][33];
  int t = threadIdx.x;
  int chunk = blockIdx.x, bh = blockIdx.y;
  int b = bh >> 3, h = bh & 7;
  #pragma unroll
  for (int i = 0; i < 8; i++){
    int e = t + 256*i;
    otl[e>>6][e&63] = ot[(size_t)bh*2048 + e];
  }
  int n0 = chunk*128;
  int nsub = t >> 6, d = t & 63;
  for (int s = 0; s < 32; s++){
    __syncthreads();
    if (t < 128) swl[t>>5][t&31] = sw[((size_t)bh*8192 + n0 + s*4 + (t>>5))*32 + (t&31)];
    __syncthreads();
    float a2 = 0.f;
    #pragma unroll
    for (int g = 0; g < 32; g++) a2 += otl[g][d] * swl[nsub][g];
    int n = n0 + s*4 + nsub;
    outb[((size_t)(b*8192 + n))*512 + h*64 + d] = (__bf16)a2;
  }
}

// ---------------- final head ----------------
__global__ __launch_bounds__(256) void head_k(const float* __restrict__ x, const float* __restrict__ g,
                                              const float* __restrict__ b, const float* __restrict__ Wout,
                                              const float* __restrict__ bout, float* __restrict__ out)
{
  int w = threadIdx.x >> 6, lane = threadIdx.x & 63;
  int row = blockIdx.x*4 + w;
  const float* xr = x + (size_t)row*512 + lane*8;
  float v[8];
  *(f32x4*)&v[0] = *(const f32x4*)xr;
  *(f32x4*)&v[4] = *(const f32x4*)(xr + 4);
  float s = 0.f, sq = 0.f;
  #pragma unroll
  for (int e = 0; e < 8; e++){ s += v[e]; sq += v[e]*v[e]; }
  #pragma unroll
  for (int off = 32; off; off >>= 1){ s += __shfl_xor(s, off); sq += __shfl_xor(sq, off); }
  float mean = s * (1.f/512.f);
  float rstd = rsqrtf(sq * (1.f/512.f) - mean*mean + 1e-5f);
  float o[4] = {0,0,0,0};
  #pragma unroll
  for (int e = 0; e < 8; e++){
    int c = lane*8 + e;
    float yn = (v[e]-mean)*rstd*g[c] + b[c];
    const float* wr = Wout + (size_t)c*4;
    o[0] += yn*wr[0]; o[1] += yn*wr[1]; o[2] += yn*wr[2]; o[3] += yn*wr[3];
  }
  #pragma unroll
  for (int off = 32; off; off >>= 1){
    #pragma unroll
    for (int j = 0; j < 4; j++) o[j] += __shfl_xor(o[j], off);
  }
  if (lane == 0){
    #pragma unroll
    for (int j = 0; j < 4; j++) out[(size_t)row*4 + j] = o[j] + bout[j];
  }
}

extern "C" void kernel_launch(void* const* d_in, const int* in_sizes, int n_in,
                              void* d_out, int out_size, void* d_ws, size_t ws_size,
                              hipStream_t stream)
{
  const float* fun    = (const float*)d_in[0];
  const float* emb    = (const float*)d_in[1];
  const float* W_pre1 = (const float*)d_in[2];
  const float* b_pre1 = (const float*)d_in[3];
  const float* W_pre2 = (const float*)d_in[4];
  const float* b_pre2 = (const float*)d_in[5];
  const float* placeholder = (const float*)d_in[6];
  const float* ln1_g  = (const float*)d_in[7];
  const float* ln1_b  = (const float*)d_in[8];
  const float* Wfx    = (const float*)d_in[9];
  const float* bfx    = (const float*)d_in[10];
  const float* Wx     = (const float*)d_in[11];
  const float* bx     = (const float*)d_in[12];
  const float* Wslice = (const float*)d_in[13];
  const float* bslice = (const float*)d_in[14];
  const float* temp   = (const float*)d_in[15];
  const float* Wq     = (const float*)d_in[16];
  const float* Wk     = (const float*)d_in[17];
  const float* Wv     = (const float*)d_in[18];
  const float* Wo     = (const float*)d_in[19];
  const float* bo     = (const float*)d_in[20];
  const float* ln2_g  = (const float*)d_in[21];
  const float* ln2_b  = (const float*)d_in[22];
  const float* Wm1    = (const float*)d_in[23];
  const float* bm1    = (const float*)d_in[24];
  const float* Wm2    = (const float*)d_in[25];
  const float* bm2    = (const float*)d_in[26];
  const float* lnf_g  = (const float*)d_in[27];
  const float* lnf_b  = (const float*)d_in[28];
  const float* Wout   = (const float*)d_in[29];
  const float* bout   = (const float*)d_in[30];

  char* ws = (char*)d_ws;
  float*  fx     = (float*)(ws + OFF_FX);
  __bf16* hbf    = (__bf16*)(ws + OFF_H);
  float*  comb   = (float*)(ws + OFF_COMB);
  float*  sw     = (float*)(ws + OFF_SW);
  __bf16* mlph   = (__bf16*)(ws + OFF_MLPH);
  __bf16* h1bf   = (__bf16*)(ws + OFF_H1);
  __bf16* outb   = (__bf16*)(ws + OFF_OUTB);
  float*  pt     = (float*)(ws + OFF_PT);
  float*  ptm    = (float*)(ws + OFF_PTM);
  float*  ot     = (float*)(ws + OFF_OT);
  __bf16* Wpre2t = (__bf16*)(ws + OFF_WT);
  __bf16* Btcat  = (__bf16*)(ws + OFF_WT + 1048576);
  __bf16* Wot    = (__bf16*)(ws + OFF_WT + 4194304);
  __bf16* Wm1t   = (__bf16*)(ws + OFF_WT + 6291456);
  __bf16* Wm2t   = (__bf16*)(ws + OFF_WT + 14680064);
  float*  bcat   = (float*)(ws + OFF_BIAS);
  float*  bpre2p = (float*)(ws + OFF_BIAS + 4*768*4);

  // ---- weight prep ----
  wtrans_k<<<dim3(16,8,1), 256,0,stream>>>(W_pre2, Wpre2t, 1024, 512, 0, 0);
  wtrans_k<<<dim3(8,8,4),  256,0,stream>>>(Wfx, Btcat, 512, 512, 262144, 393216);  // rows 0-511 of each cat
  wtrans_k<<<dim3(8,8,4),  256,0,stream>>>(Wo,  Wot,  512, 512, 262144, 262144);
  wtrans_k<<<dim3(8,32,4), 256,0,stream>>>(Wm1, Wm1t, 512, 2048, 1048576, 1048576);
  wtrans_k<<<dim3(32,8,4), 256,0,stream>>>(Wm2, Wm2t, 2048, 512, 1048576, 1048576);
  prep_wxs_k<<<dim3(256,4),128,0,stream>>>(Wx, Wslice, bx, bslice, temp, Btcat, bcat);
  bias_setup_k<<<10,256,0,stream>>>(b_pre2, placeholder, bfx, bpre2p, bcat);

  // ---- preprocess ----
  preproc1_k<<<4096,256,0,stream>>>(fun, emb, W_pre1, b_pre1, h1bf);
  // K=1024 (lgK=10, lgni=5), N=512, ntot=512
  gemm_persist<0><<<512,256,0,stream>>>(h1bf, Wpre2t, bpre2p, nullptr, (void*)fx, 512, 10, 5, 512);

  // ---- layers ----
  for (int l = 0; l < 4; l++){
    ln_k<<<4096,256,0,stream>>>(fx, ln1_g + l*512, ln1_b + l*512, hbf);
    // K=512 (lgK=9, lgni=4), N=768, ntot=768
    gemm_persist<0><<<512,256,0,stream>>>(hbf, Btcat + (size_t)l*393216, bcat + l*768, nullptr, (void*)comb, 768, 9, 4, 768);
    softmax_k<<<512,256,0,stream>>>(comb, sw);
    token_part_k<<<dim3(16,16),256,0,stream>>>(comb, sw, pt, ptm);
    attn_k<<<16,256,0,stream>>>(pt, ptm, Wq + l*4096, Wk + l*4096, Wv + l*4096, ot);
    deslice_k<<<dim3(64,16),256,0,stream>>>(ot, sw, outb);
    // K=512, N=512, ntot=512
    gemm_persist<2><<<512,256,0,stream>>>(outb, Wot + (size_t)l*262144, bo + l*512, fx, (void*)fx, 512, 9, 4, 512);
    ln_k<<<4096,256,0,stream>>>(fx, ln2_g + l*512, ln2_b + l*512, hbf);
    // K=512, N=2048, ntot=2048
    gemm_persist<1><<<512,256,0,stream>>>(hbf, Wm1t + (size_t)l*1048576, bm1 + l*2048, nullptr, (void*)mlph, 2048, 9, 4, 2048);
    // K=2048 (lgK=11, lgni=6), N=512, ntot=512
    gemm_persist<2><<<512,256,0,stream>>>(mlph, Wm2t + (size_t)l*1048576, bm2 + l*512, fx, (void*)fx, 512, 11, 6, 512);
  }

  // ---- head ----
  head_k<<<4096,256,0,stream>>>(fx, lnf_g, lnf_b, Wout, bout, (float*)d_out);
}

// Round 6
// 1439.366 us; speedup vs baseline: 1.1574x; 1.1574x over previous
//
#include <hip/hip_runtime.h>
#include <hip/hip_bf16.h>
#include <cstdint>
#include <cstddef>

typedef float  f32x4  __attribute__((ext_vector_type(4)));
typedef __bf16 bf16x8 __attribute__((ext_vector_type(8)));

#define DEV __device__ __forceinline__

DEV float gelu_f(float x){ return 0.5f * x * (1.0f + erff(x * 0.70710678118654752f)); }

// async global->LDS, 16B/lane; LDS dest = wave-uniform base + lane*16
DEV void gl16(void* lds, const void* g){
  __builtin_amdgcn_global_load_lds((const __attribute__((address_space(1))) void*)g,
                                   (__attribute__((address_space(3))) void*)lds, 16, 0, 0);
}

// ---------------- workspace layout (bytes) ----------------
static constexpr size_t OFF_FX     = 0;                       // fx fp32 [16384,512]     33554432
static constexpr size_t OFF_H      = 33554432;                // h bf16 [16384,512]      16777216
static constexpr size_t OFF_REGA   = 50331648;                // 67108864 region
static constexpr size_t OFF_COMB   = OFF_REGA;                // fp32 [16384,768] (fx_mid 0-511 | logits 512-767)
static constexpr size_t OFF_SW     = OFF_REGA + 50331648;     // fp32 [16,8192,32]       16777216
static constexpr size_t OFF_MLPH   = OFF_REGA;                // bf16 [16384,2048] (after comb/sw dead)
static constexpr size_t OFF_H1     = OFF_REGA;                // bf16 [16384,1024] (preprocess only)
static constexpr size_t OFF_OUTB   = OFF_REGA + 67108864;     // bf16 [16384,512]        16777216
static constexpr size_t OFF_PT     = OFF_OUTB + 16777216;     // fp32 [16,16,32,64]      2097152
static constexpr size_t OFF_PTM    = OFF_PT + 2097152;        // fp32 [16,16,32]         32768
static constexpr size_t OFF_OT     = OFF_PTM + 32768;         // fp32 [16,32,64]         131072
static constexpr size_t OFF_WT     = OFF_OT + 131072;         // bf16 weights (22 MB)
static constexpr size_t OFF_BIAS   = OFF_WT + 23068672;       // bcat[4][768] f32, then bpre2p[512] f32

// ---------------- weight prep ----------------
__global__ __launch_bounds__(256) void wtrans_k(const float* __restrict__ W, __bf16* __restrict__ Wt,
                                                int K, int N, size_t wstride, size_t wtstride)
{
  __shared__ float tile[64][65];
  W  += (size_t)blockIdx.z * wstride;
  Wt += (size_t)blockIdx.z * wtstride;
  int t = threadIdx.x;
  int k0 = blockIdx.x * 64, n0 = blockIdx.y * 64;
  #pragma unroll
  for (int i = 0; i < 16; i++){
    int e = t + 256*i; int kk = e >> 6, nn = e & 63;
    tile[kk][nn] = W[(size_t)(k0+kk)*N + n0+nn];
  }
  __syncthreads();
  #pragma unroll
  for (int i = 0; i < 16; i++){
    int e = t + 256*i; int nn = e >> 6, kk = e & 63;
    Wt[(size_t)(n0+nn)*K + k0+kk] = (__bf16)tile[kk][nn];
  }
}

// Wxst -> rows 512+hg of Btcat[l]; blog -> bcat[l][512+hg]
__global__ __launch_bounds__(128) void prep_wxs_k(const float* __restrict__ Wx, const float* __restrict__ Wsl,
                                                  const float* __restrict__ bx, const float* __restrict__ bsl,
                                                  const float* __restrict__ temp,
                                                  __bf16* __restrict__ Btcat, float* __restrict__ bcat)
{
  __shared__ float wsc[64];
  int l = blockIdx.y;
  const float* Wx_l  = Wx  + (size_t)l*262144;
  const float* Wsl_l = Wsl + l*2048;
  const float* bx_l  = bx  + l*512;
  const float* bsl_l = bsl + l*32;
  __bf16* Wt_l = Btcat + (size_t)l*393216 + (size_t)512*512;
  float* blog_l = bcat + l*768 + 512;
  int hg = blockIdx.x; int h = hg >> 5, g = hg & 31;
  int t = threadIdx.x;
  if (t < 64) wsc[t] = Wsl_l[t*32 + g];
  __syncthreads();
  float invt = 1.0f / temp[l*8 + h];
  #pragma unroll
  for (int cc = 0; cc < 4; cc++){
    int c = t + cc*128;
    float a = 0.f;
    for (int d = 0; d < 64; d++) a += Wx_l[(size_t)c*512 + h*64 + d] * wsc[d];
    Wt_l[(size_t)hg*512 + c] = (__bf16)(a * invt);
  }
  if (t == 0){
    float a = 0.f;
    for (int d = 0; d < 64; d++) a += bx_l[h*64 + d] * wsc[d];
    blog_l[hg] = (a + bsl_l[g]) * invt;
  }
}

__global__ __launch_bounds__(256) void bias_setup_k(const float* __restrict__ b_pre2, const float* __restrict__ placeholder,
                                                    const float* __restrict__ bfx,
                                                    float* __restrict__ bpre2p, float* __restrict__ bcat)
{
  int i = blockIdx.x*256 + threadIdx.x;   // 0..2559
  if (i < 512) bpre2p[i] = b_pre2[i] + placeholder[i];
  else if (i < 2560){
    int j = i - 512; int l = j >> 9, c = j & 511;
    bcat[l*768 + c] = bfx[l*512 + c];
  }
}

// ---------------- preprocess stage 1 ----------------
__global__ __launch_bounds__(256) void preproc1_k(const float* __restrict__ fun, const float* __restrict__ emb,
                                                  const float* __restrict__ W1, const float* __restrict__ b1,
                                                  __bf16* __restrict__ h1)
{
  __shared__ float w1l[10][1024];
  int t = threadIdx.x;
  for (int i = t*4; i < 10240; i += 1024) *(f32x4*)&w1l[0][i] = *(const f32x4*)&W1[i];
  __syncthreads();
  f32x4 bv = *(const f32x4*)&b1[t*4];
  int r0 = blockIdx.x * 4;
  for (int r = 0; r < 4; r++){
    int m = r0 + r;
    const float* er = emb + (size_t)m*3;
    const float* fr = fun + (size_t)m*7;
    float x[10];
    x[0]=er[0]; x[1]=er[1]; x[2]=er[2];
    #pragma unroll
    for (int c = 0; c < 7; c++) x[3+c] = fr[c];
    f32x4 acc = bv;
    #pragma unroll
    for (int c = 0; c < 10; c++){
      f32x4 wv = *(const f32x4*)&w1l[c][t*4];
      acc += x[c] * wv;
    }
    __bf16* op = h1 + (size_t)m*1024 + t*4;
    #pragma unroll
    for (int e = 0; e < 4; e++) op[e] = (__bf16)gelu_f(acc[e]);
  }
}

// ---------------- wide-tile MFMA GEMM: 256xBN block (512 thr, 8 waves), triple-buffered gl_lds ----------------
// D[M,N] = A[M,K]@Bt[N,K]^T + epilogue.  Rationale (R6): per-CU vmem delivery caps at ~10 B/cyc;
// staged bytes/FLOP scale as (1/BM+1/BN), so 256-wide tiles halve the staging-bound time vs 128^2.
// LDS fragment-order unified array: subtiles 0-15 = A rows, 16..S-1 = B rows. Branch-free tail
// (no junk prefetch traffic): steady wait vmcnt(2Q), tail vmcnt(Q), last vmcnt(0).
template<int EPI, int BN>
__global__ __launch_bounds__(512) void gemm_wide(const __bf16* __restrict__ A, const __bf16* __restrict__ Bt,
                                                 const float* __restrict__ bias, const float* __restrict__ res,
                                                 void* __restrict__ outp, int N, int lgK)
{
  constexpr int NSUB_B = BN/16;            // 16 (BN=256) or 8 (BN=128)
  constexpr int S = 16 + NSUB_B;           // 32 or 24 subtiles per stage
  constexpr int Q = S/8;                   // gl16 per wave per stage: 4 or 3
  constexpr int NJ = BN/32;                // n-frags per wave: 8 or 4
  __shared__ bf16x8 ldsAB[3][S][64];       // [buf][subtile][lane]; lane->(row=sub*16+(l&15), k=(l>>4)*8+j)
  const int tid = threadIdx.x;
  const int w = tid >> 6, lane = tid & 63;
  const int lm = lane & 15, lq = lane >> 4;
  const int wr = w >> 1, wc = w & 1;       // wave grid 4x2; wave tile 64 x (BN/2)
  const int m0 = blockIdx.x * 256, n0 = blockIdx.y * BN;
  const int niter = 1 << (lgK - 5);

  auto issue = [&](int i){
    unsigned buf = (unsigned)i % 3u;
    int kk = i << 5;
    #pragma unroll
    for (int q = 0; q < Q; q++){
      int f = w*Q + q;                     // flat subtile index (wave-uniform)
      const __bf16* p = (f < 16)
        ? A  + (((size_t)(m0 + f*16 + lm)) << lgK) + kk + lq*8
        : Bt + (((size_t)(n0 + (f-16)*16 + lm)) << lgK) + kk + lq*8;
      gl16(&ldsAB[buf][f][0], p);
    }
  };

  issue(0); issue(1);

  f32x4 acc[4][NJ] = {};

  for (int i = 0; i < niter; ++i){
    if (i + 2 < niter){
      issue(i + 2);
      if constexpr (Q == 4) __builtin_amdgcn_s_waitcnt(0x0F78);  // vmcnt(8)
      else                  __builtin_amdgcn_s_waitcnt(0x0F76);  // vmcnt(6)
    } else if (i + 1 < niter){
      if constexpr (Q == 4) __builtin_amdgcn_s_waitcnt(0x0F74);  // vmcnt(4)
      else                  __builtin_amdgcn_s_waitcnt(0x0F73);  // vmcnt(3)
    } else {
      __builtin_amdgcn_s_waitcnt(0x0F70);                        // vmcnt(0)
    }
    __builtin_amdgcn_s_barrier();          // stage i resident for all waves
    const unsigned buf = (unsigned)i % 3u;
    bf16x8 af[4], bfr[NJ];
    #pragma unroll
    for (int ii = 0; ii < 4; ii++)  af[ii]  = ldsAB[buf][wr*4 + ii][lane];
    #pragma unroll
    for (int jj = 0; jj < NJ; jj++) bfr[jj] = ldsAB[buf][16 + wc*NJ + jj][lane];
    #pragma unroll
    for (int ii = 0; ii < 4; ii++)
      #pragma unroll
      for (int jj = 0; jj < NJ; jj++)
        acc[ii][jj] = __builtin_amdgcn_mfma_f32_16x16x32_bf16(af[ii], bfr[jj], acc[ii][jj], 0, 0, 0);
    __builtin_amdgcn_s_barrier();          // stage i consumed before its buffer is re-targeted
  }

  #pragma unroll
  for (int ii = 0; ii < 4; ii++){
    int row0 = m0 + wr*64 + ii*16 + lq*4;
    #pragma unroll
    for (int jj = 0; jj < NJ; jj++){
      int col = n0 + wc*(BN/2) + jj*16 + lm;
      float bv = bias[col];
      #pragma unroll
      for (int r = 0; r < 4; r++){
        size_t idx = (size_t)(row0 + r)*N + col;
        float v = acc[ii][jj][r] + bv;
        if (EPI == 2) v += res[idx];
        if (EPI == 1) ((__bf16*)outp)[idx] = (__bf16)gelu_f(v);
        else          ((float*)outp)[idx]  = v;
      }
    }
  }
}

// ---------------- LayerNorm (512 cols), fp32 in -> bf16 out; 1 wave/row ----------------
__global__ __launch_bounds__(256) void ln_k(const float* __restrict__ x, const float* __restrict__ g,
                                            const float* __restrict__ b, __bf16* __restrict__ out)
{
  int w = threadIdx.x >> 6, lane = threadIdx.x & 63;
  int row = blockIdx.x*4 + w;
  const float* xr = x + (size_t)row*512 + lane*8;
  float v[8];
  *(f32x4*)&v[0] = *(const f32x4*)xr;
  *(f32x4*)&v[4] = *(const f32x4*)(xr + 4);
  float s = 0.f, sq = 0.f;
  #pragma unroll
  for (int e = 0; e < 8; e++){ s += v[e]; sq += v[e]*v[e]; }
  #pragma unroll
  for (int off = 32; off; off >>= 1){ s += __shfl_xor(s, off); sq += __shfl_xor(sq, off); }
  float mean = s * (1.f/512.f);
  float var  = sq * (1.f/512.f) - mean*mean;
  float rstd = rsqrtf(var + 1e-5f);
  float gv[8], bv[8];
  *(f32x4*)&gv[0] = *(const f32x4*)(g + lane*8);
  *(f32x4*)&gv[4] = *(const f32x4*)(g + lane*8 + 4);
  *(f32x4*)&bv[0] = *(const f32x4*)(b + lane*8);
  *(f32x4*)&bv[4] = *(const f32x4*)(b + lane*8 + 4);
  __bf16* op = out + (size_t)row*512 + lane*8;
  #pragma unroll
  for (int e = 0; e < 8; e++) op[e] = (__bf16)((v[e]-mean)*rstd*gv[e] + bv[e]);
}

// ---------------- slice softmax: comb[m][512+h*32+g] -> sw[(b*8+h)][n][g] ----------------
__global__ __launch_bounds__(256) void softmax_k(const float* __restrict__ comb, float* __restrict__ sw)
{
  int gid = blockIdx.x*256 + threadIdx.x;   // 16384*8
  int m = gid >> 3, h = gid & 7;
  const float* lp = comb + (size_t)m*768 + 512 + h*32;
  float x[32];
  #pragma unroll
  for (int i = 0; i < 8; i++) *(f32x4*)&x[i*4] = *(const f32x4*)(lp + i*4);
  float mx = x[0];
  #pragma unroll
  for (int i = 1; i < 32; i++) mx = fmaxf(mx, x[i]);
  float s = 0.f;
  #pragma unroll
  for (int i = 0; i < 32; i++){ x[i] = expf(x[i]-mx); s += x[i]; }
  float inv = 1.f / s;
  int b = m >> 13, n = m & 8191;
  float* op = sw + ((size_t)(b*8 + h)*8192 + n)*32;
  #pragma unroll
  for (int i = 0; i < 8; i++){
    f32x4 t = *(f32x4*)&x[i*4];
    t *= inv;
    *(f32x4*)(op + i*4) = t;
  }
}

// ---------------- token partial: per (chunk, bh) accumulate sw^T @ fx_mid over 512 n ----------------
__global__ __launch_bounds__(256) void token_part_k(const float* __restrict__ comb, const float* __restrict__ sw,
                                                    float* __restrict__ pt, float* __restrict__ ptm)
{
  __shared__ float fxl[32][64];
  __shared__ float swl[32][32];
  int t = threadIdx.x;
  int chunk = blockIdx.x, bh = blockIdx.y;
  int b = bh >> 3, h = bh & 7;
  int d = t & 63, gg = (t >> 6) * 8;
  float acc[8] = {0,0,0,0,0,0,0,0};
  float macc = 0.f;
  for (int s = 0; s < 16; s++){
    int nbase = chunk*512 + s*32;
    __syncthreads();
    #pragma unroll
    for (int i = 0; i < 2; i++){
      int e = t + 256*i; int rv = e >> 4, c4 = e & 15;
      *(f32x4*)&fxl[rv][c4*4] = *(const f32x4*)&comb[((size_t)b*8192 + nbase + rv)*768 + h*64 + c4*4];
    }
    { int rv = t >> 3, c4 = t & 7;
      *(f32x4*)&swl[rv][c4*4] = *(const f32x4*)&sw[((size_t)bh*8192 + nbase + rv)*32 + c4*4]; }
    __syncthreads();
    for (int nn = 0; nn < 32; nn++){
      float f = fxl[nn][d];
      #pragma unroll
      for (int jj = 0; jj < 8; jj++) acc[jj] += f * swl[nn][gg+jj];
    }
    if (t < 32){ for (int nn = 0; nn < 32; nn++) macc += swl[nn][t]; }
  }
  int cb = chunk*16 + bh;
  #pragma unroll
  for (int jj = 0; jj < 8; jj++)
    pt[((size_t)cb*32 + gg + jj)*64 + d] = acc[jj];
  if (t < 32) ptm[cb*32 + t] = macc;
}

// ---------------- token reduce + tiny attention per (b,h), fused ----------------
__global__ __launch_bounds__(256) void attn_k(const float* __restrict__ pt, const float* __restrict__ ptm,
                                              const float* __restrict__ Wq, const float* __restrict__ Wk,
                                              const float* __restrict__ Wv, float* __restrict__ ot)
{
  __shared__ float tok[32][64];
  __shared__ float ml[32];
  __shared__ float qq[32][65], kk2[32][65], vv[32][65];
  __shared__ float at[32][33];
  int t = threadIdx.x, bh = blockIdx.x;
  if (t < 32){
    float s = 0.f;
    for (int c = 0; c < 16; c++) s += ptm[(c*16 + bh)*32 + t];
    ml[t] = s + 1e-5f;
  }
  __syncthreads();
  #pragma unroll
  for (int i = 0; i < 8; i++){
    int e = t + 256*i; int g = e >> 6, d = e & 63;
    float s = 0.f;
    for (int c = 0; c < 16; c++) s += pt[((size_t)(c*16 + bh)*32 + g)*64 + d];
    tok[g][d] = s / ml[g];
  }
  __syncthreads();
  #pragma unroll
  for (int i = 0; i < 8; i++){
    int e = t + 256*i; int g = e >> 6, j = e & 63;
    float aq = 0.f, ak = 0.f, av = 0.f;
    for (int d = 0; d < 64; d++){
      float tv = tok[g][d];
      aq += tv * Wq[d*64 + j];
      ak += tv * Wk[d*64 + j];
      av += tv * Wv[d*64 + j];
    }
    qq[g][j] = aq; kk2[g][j] = ak; vv[g][j] = av;
  }
  __syncthreads();
  #pragma unroll
  for (int i = 0; i < 4; i++){
    int e = t + 256*i; int g = e >> 5, j2 = e & 31;
    float s2 = 0.f;
    for (int d = 0; d < 64; d++) s2 += qq[g][d] * kk2[j2][d];
    at[g][j2] = s2 * 0.125f;
  }
  __syncthreads();
  if (t < 32){
    float mx = at[t][0];
    for (int j = 1; j < 32; j++) mx = fmaxf(mx, at[t][j]);
    float ss = 0.f;
    for (int j = 0; j < 32; j++){ float e2 = expf(at[t][j]-mx); at[t][j] = e2; ss += e2; }
    float inv = 1.f / ss;
    for (int j = 0; j < 32; j++) at[t][j] *= inv;
  }
  __syncthreads();
  #pragma unroll
  for (int i = 0; i < 8; i++){
    int e = t + 256*i; int g = e >> 6, d = e & 63;
    float s3 = 0.f;
    for (int j = 0; j < 32; j++) s3 += at[g][j] * vv[j][d];
    ot[(size_t)bh*2048 + e] = s3;
  }
}

// ---------------- de-slice ----------------
__global__ __launch_bounds__(256) void deslice_k(const float* __restrict__ ot, const float* __restrict__ sw,
                                                 __bf16* __restrict__ outb)
{
  __shared__ float otl[32][64];
  __shared__ float swl[4][33];
  int t = threadIdx.x;
  int chunk = blockIdx.x, bh = blockIdx.y;
  int b = bh >> 3, h = bh & 7;
  #pragma unroll
  for (int i = 0; i < 8; i++){
    int e = t + 256*i;
    otl[e>>6][e&63] = ot[(size_t)bh*2048 + e];
  }
  int n0 = chunk*128;
  int nsub = t >> 6, d = t & 63;
  for (int s = 0; s < 32; s++){
    __syncthreads();
    if (t < 128) swl[t>>5][t&31] = sw[((size_t)bh*8192 + n0 + s*4 + (t>>5))*32 + (t&31)];
    __syncthreads();
    float a2 = 0.f;
    #pragma unroll
    for (int g = 0; g < 32; g++) a2 += otl[g][d] * swl[nsub][g];
    int n = n0 + s*4 + nsub;
    outb[((size_t)(b*8192 + n))*512 + h*64 + d] = (__bf16)a2;
  }
}

// ---------------- final head ----------------
__global__ __launch_bounds__(256) void head_k(const float* __restrict__ x, const float* __restrict__ g,
                                              const float* __restrict__ b, const float* __restrict__ Wout,
                                              const float* __restrict__ bout, float* __restrict__ out)
{
  int w = threadIdx.x >> 6, lane = threadIdx.x & 63;
  int row = blockIdx.x*4 + w;
  const float* xr = x + (size_t)row*512 + lane*8;
  float v[8];
  *(f32x4*)&v[0] = *(const f32x4*)xr;
  *(f32x4*)&v[4] = *(const f32x4*)(xr + 4);
  float s = 0.f, sq = 0.f;
  #pragma unroll
  for (int e = 0; e < 8; e++){ s += v[e]; sq += v[e]*v[e]; }
  #pragma unroll
  for (int off = 32; off; off >>= 1){ s += __shfl_xor(s, off); sq += __shfl_xor(sq, off); }
  float mean = s * (1.f/512.f);
  float rstd = rsqrtf(sq * (1.f/512.f) - mean*mean + 1e-5f);
  float o[4] = {0,0,0,0};
  #pragma unroll
  for (int e = 0; e < 8; e++){
    int c = lane*8 + e;
    float yn = (v[e]-mean)*rstd*g[c] + b[c];
    const float* wr = Wout + (size_t)c*4;
    o[0] += yn*wr[0]; o[1] += yn*wr[1]; o[2] += yn*wr[2]; o[3] += yn*wr[3];
  }
  #pragma unroll
  for (int off = 32; off; off >>= 1){
    #pragma unroll
    for (int j = 0; j < 4; j++) o[j] += __shfl_xor(o[j], off);
  }
  if (lane == 0){
    #pragma unroll
    for (int j = 0; j < 4; j++) out[(size_t)row*4 + j] = o[j] + bout[j];
  }
}

extern "C" void kernel_launch(void* const* d_in, const int* in_sizes, int n_in,
                              void* d_out, int out_size, void* d_ws, size_t ws_size,
                              hipStream_t stream)
{
  const float* fun    = (const float*)d_in[0];
  const float* emb    = (const float*)d_in[1];
  const float* W_pre1 = (const float*)d_in[2];
  const float* b_pre1 = (const float*)d_in[3];
  const float* W_pre2 = (const float*)d_in[4];
  const float* b_pre2 = (const float*)d_in[5];
  const float* placeholder = (const float*)d_in[6];
  const float* ln1_g  = (const float*)d_in[7];
  const float* ln1_b  = (const float*)d_in[8];
  const float* Wfx    = (const float*)d_in[9];
  const float* bfx    = (const float*)d_in[10];
  const float* Wx     = (const float*)d_in[11];
  const float* bx     = (const float*)d_in[12];
  const float* Wslice = (const float*)d_in[13];
  const float* bslice = (const float*)d_in[14];
  const float* temp   = (const float*)d_in[15];
  const float* Wq     = (const float*)d_in[16];
  const float* Wk     = (const float*)d_in[17];
  const float* Wv     = (const float*)d_in[18];
  const float* Wo     = (const float*)d_in[19];
  const float* bo     = (const float*)d_in[20];
  const float* ln2_g  = (const float*)d_in[21];
  const float* ln2_b  = (const float*)d_in[22];
  const float* Wm1    = (const float*)d_in[23];
  const float* bm1    = (const float*)d_in[24];
  const float* Wm2    = (const float*)d_in[25];
  const float* bm2    = (const float*)d_in[26];
  const float* lnf_g  = (const float*)d_in[27];
  const float* lnf_b  = (const float*)d_in[28];
  const float* Wout   = (const float*)d_in[29];
  const float* bout   = (const float*)d_in[30];

  char* ws = (char*)d_ws;
  float*  fx     = (float*)(ws + OFF_FX);
  __bf16* hbf    = (__bf16*)(ws + OFF_H);
  float*  comb   = (float*)(ws + OFF_COMB);
  float*  sw     = (float*)(ws + OFF_SW);
  __bf16* mlph   = (__bf16*)(ws + OFF_MLPH);
  __bf16* h1bf   = (__bf16*)(ws + OFF_H1);
  __bf16* outb   = (__bf16*)(ws + OFF_OUTB);
  float*  pt     = (float*)(ws + OFF_PT);
  float*  ptm    = (float*)(ws + OFF_PTM);
  float*  ot     = (float*)(ws + OFF_OT);
  __bf16* Wpre2t = (__bf16*)(ws + OFF_WT);
  __bf16* Btcat  = (__bf16*)(ws + OFF_WT + 1048576);
  __bf16* Wot    = (__bf16*)(ws + OFF_WT + 4194304);
  __bf16* Wm1t   = (__bf16*)(ws + OFF_WT + 6291456);
  __bf16* Wm2t   = (__bf16*)(ws + OFF_WT + 14680064);
  float*  bcat   = (float*)(ws + OFF_BIAS);
  float*  bpre2p = (float*)(ws + OFF_BIAS + 4*768*4);

  // ---- weight prep ----
  wtrans_k<<<dim3(16,8,1), 256,0,stream>>>(W_pre2, Wpre2t, 1024, 512, 0, 0);
  wtrans_k<<<dim3(8,8,4),  256,0,stream>>>(Wfx, Btcat, 512, 512, 262144, 393216);  // rows 0-511 of each cat
  wtrans_k<<<dim3(8,8,4),  256,0,stream>>>(Wo,  Wot,  512, 512, 262144, 262144);
  wtrans_k<<<dim3(8,32,4), 256,0,stream>>>(Wm1, Wm1t, 512, 2048, 1048576, 1048576);
  wtrans_k<<<dim3(32,8,4), 256,0,stream>>>(Wm2, Wm2t, 2048, 512, 1048576, 1048576);
  prep_wxs_k<<<dim3(256,4),128,0,stream>>>(Wx, Wslice, bx, bslice, temp, Btcat, bcat);
  bias_setup_k<<<10,256,0,stream>>>(b_pre2, placeholder, bfx, bpre2p, bcat);

  // ---- preprocess ----
  preproc1_k<<<4096,256,0,stream>>>(fun, emb, W_pre1, b_pre1, h1bf);
  // M=16384, N=512, K=1024 -> 256x128 tiles, grid 64x4
  gemm_wide<0,128><<<dim3(64,4),512,0,stream>>>(h1bf, Wpre2t, bpre2p, nullptr, (void*)fx, 512, 10);

  // ---- layers ----
  for (int l = 0; l < 4; l++){
    ln_k<<<4096,256,0,stream>>>(fx, ln1_g + l*512, ln1_b + l*512, hbf);
    // N=768, K=512 -> 256x256 tiles, grid 64x3
    gemm_wide<0,256><<<dim3(64,3),512,0,stream>>>(hbf, Btcat + (size_t)l*393216, bcat + l*768, nullptr, (void*)comb, 768, 9);
    softmax_k<<<512,256,0,stream>>>(comb, sw);
    token_part_k<<<dim3(16,16),256,0,stream>>>(comb, sw, pt, ptm);
    attn_k<<<16,256,0,stream>>>(pt, ptm, Wq + l*4096, Wk + l*4096, Wv + l*4096, ot);
    deslice_k<<<dim3(64,16),256,0,stream>>>(ot, sw, outb);
    // N=512, K=512 -> 256x128 tiles, grid 64x4
    gemm_wide<2,128><<<dim3(64,4),512,0,stream>>>(outb, Wot + (size_t)l*262144, bo + l*512, fx, (void*)fx, 512, 9);
    ln_k<<<4096,256,0,stream>>>(fx, ln2_g + l*512, ln2_b + l*512, hbf);
    // N=2048, K=512 -> 256x256 tiles, grid 64x8
    gemm_wide<1,256><<<dim3(64,8),512,0,stream>>>(hbf, Wm1t + (size_t)l*1048576, bm1 + l*2048, nullptr, (void*)mlph, 2048, 9);
    // N=512, K=2048 -> 256x128 tiles, grid 64x4
    gemm_wide<2,128><<<dim3(64,4),512,0,stream>>>(mlph, Wm2t + (size_t)l*1048576, bm2 + l*512, fx, (void*)fx, 512, 11);
  }

  // ---- head ----
  head_k<<<4096,256,0,stream>>>(fx, lnf_g, lnf_b, Wout, bout, (float*)d_out);
}